// Round 1
// baseline (485.300 us; speedup 1.0000x reference)
//
#include <hip/hip_runtime.h>
#include <stdint.h>

#define BB 2
#define HH 32
#define CC 256
#define DD 128
#define GG 2048
#define FF 128
#define NCAT (GG + CC)   // 2304
#define NSORT 4096

// ---------------------------------------------------------------------------
// Kernel 1: per-(b,h) stable descending top-G via bitonic sort of 64-bit keys.
// key = (float_bits << 12) | (4095 - j)   (values are uniform [0,1) => >= 0,
// so raw float bits are monotone; lower original index j wins ties, matching
// jax.lax.top_k). Pad keys are 0 which sort below every real entry.
// ---------------------------------------------------------------------------
__global__ __launch_bounds__(512) void sort_topk_kernel(
    const float* __restrict__ heap_val, const int* __restrict__ heap_idx,
    const float* __restrict__ score_c, const int* __restrict__ tokens_seen,
    float* __restrict__ out_val, float* __restrict__ out_idx,
    int* __restrict__ selws)
{
    __shared__ uint64_t keys[NSORT];
    const int bh  = blockIdx.x;       // 0..63
    const int tid = threadIdx.x;

    const float* hv = heap_val + (size_t)bh * GG;
    const float* sc = score_c  + (size_t)bh * CC;

    for (int i = tid; i < NSORT; i += 512) {
        uint64_t key = 0ull;
        if (i < GG) {
            uint32_t fb = __float_as_uint(hv[i]);
            key = ((uint64_t)fb << 12) | (uint64_t)(4095 - i);
        } else if (i < NCAT) {
            uint32_t fb = __float_as_uint(sc[i - GG]);
            key = ((uint64_t)fb << 12) | (uint64_t)(4095 - i);
        }
        keys[i] = key;
    }

    // Bitonic sort, descending overall.
    for (int k = 2; k <= NSORT; k <<= 1) {
        for (int j = k >> 1; j > 0; j >>= 1) {
            __syncthreads();
            for (int i = tid; i < NSORT; i += 512) {
                int ixj = i ^ j;
                if (ixj > i) {
                    uint64_t a = keys[i];
                    uint64_t b = keys[ixj];
                    bool descBlock = ((i & k) == 0);
                    bool doswap = descBlock ? (a < b) : (a > b);
                    if (doswap) { keys[i] = b; keys[ixj] = a; }
                }
            }
        }
    }
    __syncthreads();

    const int ts = tokens_seen[0];
    const int* hidx = heap_idx + (size_t)bh * GG;
    for (int g = tid; g < GG; g += 512) {
        uint64_t key = keys[g];
        int j = 4095 - (int)(key & 0xFFFull);
        out_val[(size_t)bh * GG + g] = __uint_as_float((uint32_t)(key >> 12));
        int gidx = (j < GG) ? hidx[j] : (ts + (j - GG));
        out_idx[(size_t)bh * GG + g] = (float)gidx;     // exact (<= 4351)
        selws[(size_t)bh * GG + g] = j;
    }
}

// ---------------------------------------------------------------------------
// Kernel 2: gather K_top_new / V_top_new / FK_top_new (float4 rows of 128).
// ---------------------------------------------------------------------------
__global__ __launch_bounds__(256) void gather_topk_kernel(
    const float4* __restrict__ K_top, const float4* __restrict__ V_top,
    const float4* __restrict__ FK_top,
    const float4* __restrict__ k_c, const float4* __restrict__ v_c,
    const float4* __restrict__ fk_c,
    const int* __restrict__ selws,
    float4* __restrict__ oK, float4* __restrict__ oV, float4* __restrict__ oFK)
{
    const long long ROWQ = (long long)BB * HH * GG * 32;  // quads per array
    long long t = (long long)blockIdx.x * 256 + threadIdx.x;
    int arr = (int)(t / ROWQ);
    long long rem = t - (long long)arr * ROWQ;
    int row = (int)(rem >> 5);   // 0 .. B*H*G-1
    int q   = (int)(rem & 31);
    int bh  = row >> 11;         // /G
    int j   = selws[row];

    const float4* topsrc = (arr == 0) ? K_top : ((arr == 1) ? V_top : FK_top);
    const float4* chksrc = (arr == 0) ? k_c   : ((arr == 1) ? v_c   : fk_c);
    float4*       dst    = (arr == 0) ? oK    : ((arr == 1) ? oV    : oFK);

    float4 val;
    if (j < GG) val = topsrc[((long long)bh * GG + j) * 32 + q];
    else        val = chksrc[((long long)bh * CC + (j - GG)) * 32 + q];
    dst[(long long)row * 32 + q] = val;
}

// ---------------------------------------------------------------------------
// Kernel 3: sliding window shift for K_win / V_win.
// ---------------------------------------------------------------------------
__global__ __launch_bounds__(256) void window_kernel(
    const float4* __restrict__ K_win, const float4* __restrict__ V_win,
    const float4* __restrict__ k_c, const float4* __restrict__ v_c,
    float4* __restrict__ oKw, float4* __restrict__ oVw)
{
    const int QPA = BB * HH * CC * 32;   // quads per array (524288)
    int t = blockIdx.x * 256 + threadIdx.x;
    int arr = t / QPA;
    int rem = t - arr * QPA;
    int row = rem >> 5;          // 0 .. B*H*C-1
    int q   = rem & 31;
    int bh  = row >> 8;          // /C
    int c   = row & 255;

    const float4* win = arr ? V_win : K_win;
    const float4* chk = arr ? v_c : k_c;
    float4 val = (c < CC - 1)
        ? win[((long long)bh * CC + c + 1) * 32 + q]
        : chk[((long long)bh * CC + (CC - 1)) * 32 + q];
    (arr ? oVw : oKw)[(long long)row * 32 + q] = val;
}

// ---------------------------------------------------------------------------
// Kernel 4: per-(b,h)  H_sum[f][d] = sum_g FK[g][f] * V[g][d],  S_sum[f].
// 256 threads = 16x16 tile grid, each thread an 8x8 register tile.
// ---------------------------------------------------------------------------
__global__ __launch_bounds__(256) void hsum_kernel(
    const float* __restrict__ FKn, const float* __restrict__ Vn,
    float* __restrict__ H_out, float* __restrict__ S_out)
{
    __shared__ float fk_t[16][128];
    __shared__ float v_t[16][132];     // +4 pad to soften bank conflicts
    __shared__ float s_red[256];

    const int bh  = blockIdx.x;
    const int tid = threadIdx.x;
    const float* fkb = FKn + (long long)bh * GG * FF;
    const float* vb  = Vn  + (long long)bh * GG * DD;

    float acc[8][8];
#pragma unroll
    for (int a = 0; a < 8; ++a)
#pragma unroll
        for (int b2 = 0; b2 < 8; ++b2) acc[a][b2] = 0.f;
    float s_part = 0.f;

    const int tf = tid >> 4, td = tid & 15;

    for (int t0 = 0; t0 < GG; t0 += 16) {
#pragma unroll
        for (int e = tid, it = 0; it < 8; e += 256, ++it) {
            int g = e >> 7, f = e & 127;   // f == tid & 127 (constant)
            float fv = fkb[(long long)(t0 + g) * FF + f];
            fk_t[g][f] = fv;
            s_part += fv;
            v_t[g][f] = vb[(long long)(t0 + g) * DD + f];
        }
        __syncthreads();
#pragma unroll 4
        for (int g = 0; g < 16; ++g) {
            float fa[8], vv[8];
#pragma unroll
            for (int a = 0; a < 8; ++a) fa[a] = fk_t[g][tf * 8 + a];
#pragma unroll
            for (int b2 = 0; b2 < 8; ++b2) vv[b2] = v_t[g][td * 8 + b2];
#pragma unroll
            for (int a = 0; a < 8; ++a)
#pragma unroll
                for (int b2 = 0; b2 < 8; ++b2)
                    acc[a][b2] += fa[a] * vv[b2];
        }
        __syncthreads();
    }

    float* Hb = H_out + (long long)bh * FF * DD;
#pragma unroll
    for (int a = 0; a < 8; ++a)
#pragma unroll
        for (int b2 = 0; b2 < 8; ++b2)
            Hb[(long long)(tf * 8 + a) * DD + td * 8 + b2] = acc[a][b2];

    s_red[tid] = s_part;
    __syncthreads();
    if (tid < 128)
        S_out[(long long)bh * FF + tid] = s_red[tid] + s_red[tid + 128];
}

// ---------------------------------------------------------------------------
extern "C" void kernel_launch(void* const* d_in, const int* in_sizes, int n_in,
                              void* d_out, int out_size, void* d_ws, size_t ws_size,
                              hipStream_t stream) {
    const float* k_c      = (const float*)d_in[0];
    const float* v_c      = (const float*)d_in[1];
    const float* fk_c     = (const float*)d_in[2];
    const float* score_c  = (const float*)d_in[3];
    const float* K_win    = (const float*)d_in[4];
    const float* V_win    = (const float*)d_in[5];
    const float* K_top    = (const float*)d_in[6];
    const float* V_top    = (const float*)d_in[7];
    const float* FK_top   = (const float*)d_in[8];
    const float* heap_val = (const float*)d_in[9];
    const int*   heap_idx = (const int*)d_in[10];
    const int*   tokens   = (const int*)d_in[11];

    float* out = (float*)d_out;

    // Flat float offsets of the 9 outputs, in reference return order.
    const size_t SZ_WIN = (size_t)BB * HH * CC * DD;   // 2,097,152
    const size_t SZ_TOP = (size_t)BB * HH * GG * DD;   // 16,777,216
    const size_t SZ_VAL = (size_t)BB * HH * GG;        //   131,072
    const size_t SZ_H   = (size_t)BB * HH * FF * DD;   // 1,048,576

    float* o_Kwin  = out;
    float* o_Vwin  = o_Kwin  + SZ_WIN;
    float* o_Ktop  = o_Vwin  + SZ_WIN;
    float* o_Vtop  = o_Ktop  + SZ_TOP;
    float* o_FKtop = o_Vtop  + SZ_TOP;
    float* o_val   = o_FKtop + SZ_TOP;
    float* o_idx   = o_val   + SZ_VAL;
    float* o_H     = o_idx   + SZ_VAL;
    float* o_S     = o_H     + SZ_H;

    int* selws = (int*)d_ws;   // B*H*G ints = 512 KB

    // 1) top-k selection (writes new_val, new_idx, sel permutation)
    sort_topk_kernel<<<BB * HH, 512, 0, stream>>>(
        heap_val, heap_idx, score_c, tokens, o_val, o_idx, selws);

    // 2) gather survivors into K_top_new / V_top_new / FK_top_new
    {
        long long nthreads = 3LL * BB * HH * GG * 32;  // 12,582,912
        int blocks = (int)(nthreads / 256);             // 49,152
        gather_topk_kernel<<<blocks, 256, 0, stream>>>(
            (const float4*)K_top, (const float4*)V_top, (const float4*)FK_top,
            (const float4*)k_c, (const float4*)v_c, (const float4*)fk_c,
            selws, (float4*)o_Ktop, (float4*)o_Vtop, (float4*)o_FKtop);
    }

    // 3) sliding window shift
    {
        int nthreads = 2 * BB * HH * CC * 32;          // 1,048,576
        window_kernel<<<nthreads / 256, 256, 0, stream>>>(
            (const float4*)K_win, (const float4*)V_win,
            (const float4*)k_c, (const float4*)v_c,
            (float4*)o_Kwin, (float4*)o_Vwin);
    }

    // 4) low-rank sums from the just-written FK_top_new / V_top_new
    hsum_kernel<<<BB * HH, 256, 0, stream>>>(o_FKtop, o_Vtop, o_H, o_S);
}

// Round 2
// 248.830 us; speedup vs baseline: 1.9503x; 1.9503x over previous
//
#include <hip/hip_runtime.h>
#include <stdint.h>

#define BB 2
#define HH 32
#define CC 256
#define DD 128
#define GG 2048
#define FF 128
#define NCAT (GG + CC)   // 2304
#define NSORT 4096

// ---------------------------------------------------------------------------
// Kernel 1: per-(b,h) stable descending top-G via bitonic sort of 64-bit keys.
// key = (float_bits << 12) | (4095 - j)   (values are uniform [0,1) => >= 0,
// so raw float bits are monotone; lower original index j wins ties, matching
// jax.lax.top_k). Pad keys are 0 which sort below every real entry.
// ---------------------------------------------------------------------------
__global__ __launch_bounds__(512) void sort_topk_kernel(
    const float* __restrict__ heap_val, const int* __restrict__ heap_idx,
    const float* __restrict__ score_c, const int* __restrict__ tokens_seen,
    float* __restrict__ out_val, float* __restrict__ out_idx,
    int* __restrict__ selws)
{
    __shared__ uint64_t keys[NSORT];
    const int bh  = blockIdx.x;       // 0..63
    const int tid = threadIdx.x;

    const float* hv = heap_val + (size_t)bh * GG;
    const float* sc = score_c  + (size_t)bh * CC;

    for (int i = tid; i < NSORT; i += 512) {
        uint64_t key = 0ull;
        if (i < GG) {
            uint32_t fb = __float_as_uint(hv[i]);
            key = ((uint64_t)fb << 12) | (uint64_t)(4095 - i);
        } else if (i < NCAT) {
            uint32_t fb = __float_as_uint(sc[i - GG]);
            key = ((uint64_t)fb << 12) | (uint64_t)(4095 - i);
        }
        keys[i] = key;
    }

    // Bitonic sort, descending overall.
    for (int k = 2; k <= NSORT; k <<= 1) {
        for (int j = k >> 1; j > 0; j >>= 1) {
            __syncthreads();
            for (int i = tid; i < NSORT; i += 512) {
                int ixj = i ^ j;
                if (ixj > i) {
                    uint64_t a = keys[i];
                    uint64_t b = keys[ixj];
                    bool descBlock = ((i & k) == 0);
                    bool doswap = descBlock ? (a < b) : (a > b);
                    if (doswap) { keys[i] = b; keys[ixj] = a; }
                }
            }
        }
    }
    __syncthreads();

    const int ts = tokens_seen[0];
    const int* hidx = heap_idx + (size_t)bh * GG;
    for (int g = tid; g < GG; g += 512) {
        uint64_t key = keys[g];
        int j = 4095 - (int)(key & 0xFFFull);
        out_val[(size_t)bh * GG + g] = __uint_as_float((uint32_t)(key >> 12));
        int gidx = (j < GG) ? hidx[j] : (ts + (j - GG));
        out_idx[(size_t)bh * GG + g] = (float)gidx;     // exact (<= 4351)
        selws[(size_t)bh * GG + g] = j;
    }
}

// ---------------------------------------------------------------------------
// Kernel 2: gather K_top_new / V_top_new / FK_top_new (float4 rows of 128).
// ---------------------------------------------------------------------------
__global__ __launch_bounds__(256) void gather_topk_kernel(
    const float4* __restrict__ K_top, const float4* __restrict__ V_top,
    const float4* __restrict__ FK_top,
    const float4* __restrict__ k_c, const float4* __restrict__ v_c,
    const float4* __restrict__ fk_c,
    const int* __restrict__ selws,
    float4* __restrict__ oK, float4* __restrict__ oV, float4* __restrict__ oFK)
{
    const long long ROWQ = (long long)BB * HH * GG * 32;  // quads per array
    long long t = (long long)blockIdx.x * 256 + threadIdx.x;
    int arr = (int)(t / ROWQ);
    long long rem = t - (long long)arr * ROWQ;
    int row = (int)(rem >> 5);   // 0 .. B*H*G-1
    int q   = (int)(rem & 31);
    int bh  = row >> 11;         // /G
    int j   = selws[row];

    const float4* topsrc = (arr == 0) ? K_top : ((arr == 1) ? V_top : FK_top);
    const float4* chksrc = (arr == 0) ? k_c   : ((arr == 1) ? v_c   : fk_c);
    float4*       dst    = (arr == 0) ? oK    : ((arr == 1) ? oV    : oFK);

    float4 val;
    if (j < GG) val = topsrc[((long long)bh * GG + j) * 32 + q];
    else        val = chksrc[((long long)bh * CC + (j - GG)) * 32 + q];
    dst[(long long)row * 32 + q] = val;
}

// ---------------------------------------------------------------------------
// Kernel 3: sliding window shift for K_win / V_win.
// ---------------------------------------------------------------------------
__global__ __launch_bounds__(256) void window_kernel(
    const float4* __restrict__ K_win, const float4* __restrict__ V_win,
    const float4* __restrict__ k_c, const float4* __restrict__ v_c,
    float4* __restrict__ oKw, float4* __restrict__ oVw)
{
    const int QPA = BB * HH * CC * 32;   // quads per array (524288)
    int t = blockIdx.x * 256 + threadIdx.x;
    int arr = t / QPA;
    int rem = t - arr * QPA;
    int row = rem >> 5;          // 0 .. B*H*C-1
    int q   = rem & 31;
    int bh  = row >> 8;          // /C
    int c   = row & 255;

    const float4* win = arr ? V_win : K_win;
    const float4* chk = arr ? v_c : k_c;
    float4 val = (c < CC - 1)
        ? win[((long long)bh * CC + c + 1) * 32 + q]
        : chk[((long long)bh * CC + (CC - 1)) * 32 + q];
    (arr ? oVw : oKw)[(long long)row * 32 + q] = val;
}

// ---------------------------------------------------------------------------
// Kernel 4: H_sum[f][d] = sum_g FK[g][f] * V[g][d]  (fp32),  S_sum[f].
// Grid = 256 blocks: (b,h) x 2x2 output quadrants of 64x64. 256 threads,
// each owns a 4x4 register tile over the full G=2048 with register prefetch
// of the next 32-row chunk (global loads issue before the compute phase).
// ---------------------------------------------------------------------------
__global__ __launch_bounds__(256) void hsum_kernel(
    const float4* __restrict__ FKq, const float4* __restrict__ Vq,
    float* __restrict__ H_out, float* __restrict__ S_out)
{
    __shared__ float fk_t[32][68];   // 68 keeps float4 alignment (272B rows)
    __shared__ float v_t[32][68];
    __shared__ float4 s4[256];

    const int bx  = blockIdx.x;
    const int bh  = bx >> 2;
    const int fq  = (bx >> 1) & 1;   // which 64-col half of F
    const int dq  = bx & 1;          // which 64-col half of D
    const int tid = threadIdx.x;

    const int g0 = tid >> 4;         // 0..15  (row within chunk, +16 for half 1)
    const int f4 = tid & 15;         // float4 column within the 64-wide slab

    // quad-indexed bases: row stride = 32 quads (128 floats)
    const float4* fkb = FKq + (long long)bh * GG * 32 + fq * 16 + f4;
    const float4* vb  = Vq  + (long long)bh * GG * 32 + dq * 16 + f4;

    float acc[4][4];
#pragma unroll
    for (int a = 0; a < 4; ++a)
#pragma unroll
        for (int b2 = 0; b2 < 4; ++b2) acc[a][b2] = 0.f;

    float4 s_acc = make_float4(0.f, 0.f, 0.f, 0.f);

    const int tf = tid >> 4;   // 0..15 -> f row group (4 rows each)
    const int td = tid & 15;   // 0..15 -> d col group (4 cols each)

    // prefetch chunk 0
    float4 pf_fk0 = fkb[(long long)(g0)      * 32];
    float4 pf_fk1 = fkb[(long long)(g0 + 16) * 32];
    float4 pf_v0  = vb [(long long)(g0)      * 32];
    float4 pf_v1  = vb [(long long)(g0 + 16) * 32];

    for (int c0 = 0; c0 < GG; c0 += 32) {
        __syncthreads();   // previous compute done; safe to overwrite LDS
        *(float4*)&fk_t[g0][f4 * 4]      = pf_fk0;
        *(float4*)&fk_t[g0 + 16][f4 * 4] = pf_fk1;
        *(float4*)&v_t[g0][f4 * 4]       = pf_v0;
        *(float4*)&v_t[g0 + 16][f4 * 4]  = pf_v1;
        s_acc.x += pf_fk0.x + pf_fk1.x;
        s_acc.y += pf_fk0.y + pf_fk1.y;
        s_acc.z += pf_fk0.z + pf_fk1.z;
        s_acc.w += pf_fk0.w + pf_fk1.w;
        __syncthreads();

        if (c0 + 32 < GG) {   // issue next chunk's loads; land during FMAs
            pf_fk0 = fkb[(long long)(c0 + 32 + g0)      * 32];
            pf_fk1 = fkb[(long long)(c0 + 32 + g0 + 16) * 32];
            pf_v0  = vb [(long long)(c0 + 32 + g0)      * 32];
            pf_v1  = vb [(long long)(c0 + 32 + g0 + 16) * 32];
        }

#pragma unroll 4
        for (int g = 0; g < 32; ++g) {
            float fa[4], vv[4];
#pragma unroll
            for (int a = 0; a < 4; ++a) fa[a] = fk_t[g][tf * 4 + a];
#pragma unroll
            for (int b2 = 0; b2 < 4; ++b2) vv[b2] = v_t[g][td * 4 + b2];
#pragma unroll
            for (int a = 0; a < 4; ++a)
#pragma unroll
                for (int b2 = 0; b2 < 4; ++b2)
                    acc[a][b2] += fa[a] * vv[b2];
        }
    }

    // H quadrant write (float4 rows)
    float* Hb = H_out + (long long)bh * FF * DD
              + (long long)(fq * 64 + tf * 4) * DD + dq * 64 + td * 4;
#pragma unroll
    for (int a = 0; a < 4; ++a)
        *(float4*)&Hb[(long long)a * DD] =
            make_float4(acc[a][0], acc[a][1], acc[a][2], acc[a][3]);

    // S_sum: only the dq==0 block of each f-half writes it.
    s4[tid] = s_acc;
    __syncthreads();
    if (dq == 0 && tid < 16) {
        float4 s = make_float4(0.f, 0.f, 0.f, 0.f);
#pragma unroll
        for (int r = 0; r < 16; ++r) {
            float4 p = s4[r * 16 + tid];
            s.x += p.x; s.y += p.y; s.z += p.z; s.w += p.w;
        }
        *(float4*)&S_out[(long long)bh * FF + fq * 64 + tid * 4] = s;
    }
}

// ---------------------------------------------------------------------------
extern "C" void kernel_launch(void* const* d_in, const int* in_sizes, int n_in,
                              void* d_out, int out_size, void* d_ws, size_t ws_size,
                              hipStream_t stream) {
    const float* k_c      = (const float*)d_in[0];
    const float* v_c      = (const float*)d_in[1];
    const float* fk_c     = (const float*)d_in[2];
    const float* score_c  = (const float*)d_in[3];
    const float* K_win    = (const float*)d_in[4];
    const float* V_win    = (const float*)d_in[5];
    const float* K_top    = (const float*)d_in[6];
    const float* V_top    = (const float*)d_in[7];
    const float* FK_top   = (const float*)d_in[8];
    const float* heap_val = (const float*)d_in[9];
    const int*   heap_idx = (const int*)d_in[10];
    const int*   tokens   = (const int*)d_in[11];

    float* out = (float*)d_out;

    const size_t SZ_WIN = (size_t)BB * HH * CC * DD;   // 2,097,152
    const size_t SZ_TOP = (size_t)BB * HH * GG * DD;   // 16,777,216
    const size_t SZ_VAL = (size_t)BB * HH * GG;        //   131,072
    const size_t SZ_H   = (size_t)BB * HH * FF * DD;   // 1,048,576

    float* o_Kwin  = out;
    float* o_Vwin  = o_Kwin  + SZ_WIN;
    float* o_Ktop  = o_Vwin  + SZ_WIN;
    float* o_Vtop  = o_Ktop  + SZ_TOP;
    float* o_FKtop = o_Vtop  + SZ_TOP;
    float* o_val   = o_FKtop + SZ_TOP;
    float* o_idx   = o_val   + SZ_VAL;
    float* o_H     = o_idx   + SZ_VAL;
    float* o_S     = o_H     + SZ_H;

    int* selws = (int*)d_ws;   // B*H*G ints = 512 KB

    // 1) top-k selection (writes new_val, new_idx, sel permutation)
    sort_topk_kernel<<<BB * HH, 512, 0, stream>>>(
        heap_val, heap_idx, score_c, tokens, o_val, o_idx, selws);

    // 2) gather survivors into K_top_new / V_top_new / FK_top_new
    {
        long long nthreads = 3LL * BB * HH * GG * 32;  // 12,582,912
        int blocks = (int)(nthreads / 256);             // 49,152
        gather_topk_kernel<<<blocks, 256, 0, stream>>>(
            (const float4*)K_top, (const float4*)V_top, (const float4*)FK_top,
            (const float4*)k_c, (const float4*)v_c, (const float4*)fk_c,
            selws, (float4*)o_Ktop, (float4*)o_Vtop, (float4*)o_FKtop);
    }

    // 3) sliding window shift
    {
        int nthreads = 2 * BB * HH * CC * 32;          // 1,048,576
        window_kernel<<<nthreads / 256, 256, 0, stream>>>(
            (const float4*)K_win, (const float4*)V_win,
            (const float4*)k_c, (const float4*)v_c,
            (float4*)o_Kwin, (float4*)o_Vwin);
    }

    // 4) low-rank sums from the just-written FK_top_new / V_top_new
    hsum_kernel<<<4 * BB * HH, 256, 0, stream>>>(
        (const float4*)o_FKtop, (const float4*)o_Vtop, o_H, o_S);
}

// Round 3
// 209.924 us; speedup vs baseline: 2.3118x; 1.1853x over previous
//
#include <hip/hip_runtime.h>
#include <stdint.h>

#define BB 2
#define HH 32
#define CC 256
#define DD 128
#define GG 2048
#define FF 128
#define NCAT (GG + CC)   // 2304

// ---------------------------------------------------------------------------
// Kernel 1: per-(b,h) stable descending top-G via O(n^2) ranking.
// key = (float_bits << 12) | (4095 - j): values are uniform [0,1) => >= 0,
// so raw float bits are monotone; lower original index j wins ties (matching
// jax.lax.top_k). Keys are unique => rank = #{keys > mine} is an exact
// position in the stable descending order.
// Grid: 64 slices x 9 segments = 576 blocks, 256 threads, 1 candidate/thread.
// ---------------------------------------------------------------------------
__global__ __launch_bounds__(256) void rank_topk_kernel(
    const float* __restrict__ heap_val, const int* __restrict__ heap_idx,
    const float* __restrict__ score_c, const int* __restrict__ tokens_seen,
    float* __restrict__ out_val, float* __restrict__ out_idx,
    int* __restrict__ selws)
{
    __shared__ uint64_t keys[NCAT];          // 18 KB

    const int blk = blockIdx.x;
    const int bh  = blk / 9;
    const int seg = blk - bh * 9;
    const int tid = threadIdx.x;

    const float* hv = heap_val + (size_t)bh * GG;
    const float* sc = score_c  + (size_t)bh * CC;

    for (int i = tid; i < NCAT; i += 256) {
        uint32_t fb = (i < GG) ? __float_as_uint(hv[i])
                               : __float_as_uint(sc[i - GG]);
        keys[i] = ((uint64_t)fb << 12) | (uint64_t)(4095 - i);
    }
    __syncthreads();

    const int cand = seg * 256 + tid;        // 0..2303
    const uint64_t my = keys[cand];

    int rank = 0;
    const ulonglong2* k2 = (const ulonglong2*)keys;
#pragma unroll 4
    for (int j = 0; j < NCAT / 2; ++j) {     // uniform addr -> LDS broadcast
        ulonglong2 p = k2[j];
        rank += (p.x > my) + (p.y > my);
    }

    if (rank < GG) {
        const size_t o = (size_t)bh * GG + rank;
        out_val[o] = __uint_as_float((uint32_t)(my >> 12));
        int j = 4095 - (int)(my & 0xFFFull);
        int gidx = (j < GG) ? heap_idx[(size_t)bh * GG + j]
                            : (tokens_seen[0] + (j - GG));
        out_idx[o] = (float)gidx;            // exact (<= 4351)
        selws[o] = j;
    }
}

// ---------------------------------------------------------------------------
// Kernel 2: gather K_top_new / V_top_new / FK_top_new (float4 rows of 128).
// ---------------------------------------------------------------------------
__global__ __launch_bounds__(256) void gather_topk_kernel(
    const float4* __restrict__ K_top, const float4* __restrict__ V_top,
    const float4* __restrict__ FK_top,
    const float4* __restrict__ k_c, const float4* __restrict__ v_c,
    const float4* __restrict__ fk_c,
    const int* __restrict__ selws,
    float4* __restrict__ oK, float4* __restrict__ oV, float4* __restrict__ oFK)
{
    const long long ROWQ = (long long)BB * HH * GG * 32;  // quads per array
    long long t = (long long)blockIdx.x * 256 + threadIdx.x;
    int arr = (int)(t / ROWQ);
    long long rem = t - (long long)arr * ROWQ;
    int row = (int)(rem >> 5);   // 0 .. B*H*G-1
    int q   = (int)(rem & 31);
    int bh  = row >> 11;         // /G
    int j   = selws[row];

    const float4* topsrc = (arr == 0) ? K_top : ((arr == 1) ? V_top : FK_top);
    const float4* chksrc = (arr == 0) ? k_c   : ((arr == 1) ? v_c   : fk_c);
    float4*       dst    = (arr == 0) ? oK    : ((arr == 1) ? oV    : oFK);

    float4 val;
    if (j < GG) val = topsrc[((long long)bh * GG + j) * 32 + q];
    else        val = chksrc[((long long)bh * CC + (j - GG)) * 32 + q];
    dst[(long long)row * 32 + q] = val;
}

// ---------------------------------------------------------------------------
// Kernel 3: sliding window shift for K_win / V_win.
// ---------------------------------------------------------------------------
__global__ __launch_bounds__(256) void window_kernel(
    const float4* __restrict__ K_win, const float4* __restrict__ V_win,
    const float4* __restrict__ k_c, const float4* __restrict__ v_c,
    float4* __restrict__ oKw, float4* __restrict__ oVw)
{
    const int QPA = BB * HH * CC * 32;   // quads per array (524288)
    int t = blockIdx.x * 256 + threadIdx.x;
    int arr = t / QPA;
    int rem = t - arr * QPA;
    int row = rem >> 5;          // 0 .. B*H*C-1
    int q   = rem & 31;
    int bh  = row >> 8;          // /C
    int c   = row & 255;

    const float4* win = arr ? V_win : K_win;
    const float4* chk = arr ? v_c : k_c;
    float4 val = (c < CC - 1)
        ? win[((long long)bh * CC + c + 1) * 32 + q]
        : chk[((long long)bh * CC + (CC - 1)) * 32 + q];
    (arr ? oVw : oKw)[(long long)row * 32 + q] = val;
}

// ---------------------------------------------------------------------------
// Kernel 4: H_sum[f][d] = sum_g FK[g][f] * V[g][d]  (fp32),  S_sum[f].
// Grid = 256 blocks: (b,h) x 2x2 output quadrants of 64x64. 256 threads,
// each owns a 4x4 register tile over the full G=2048 with register prefetch.
// ---------------------------------------------------------------------------
__global__ __launch_bounds__(256) void hsum_kernel(
    const float4* __restrict__ FKq, const float4* __restrict__ Vq,
    float* __restrict__ H_out, float* __restrict__ S_out)
{
    __shared__ float fk_t[32][68];   // 68 keeps float4 alignment (272B rows)
    __shared__ float v_t[32][68];
    __shared__ float4 s4[256];

    const int bx  = blockIdx.x;
    const int bh  = bx >> 2;
    const int fq  = (bx >> 1) & 1;   // which 64-col half of F
    const int dq  = bx & 1;          // which 64-col half of D
    const int tid = threadIdx.x;

    const int g0 = tid >> 4;         // 0..15  (row within chunk, +16 for half 1)
    const int f4 = tid & 15;         // float4 column within the 64-wide slab

    const float4* fkb = FKq + (long long)bh * GG * 32 + fq * 16 + f4;
    const float4* vb  = Vq  + (long long)bh * GG * 32 + dq * 16 + f4;

    float acc[4][4];
#pragma unroll
    for (int a = 0; a < 4; ++a)
#pragma unroll
        for (int b2 = 0; b2 < 4; ++b2) acc[a][b2] = 0.f;

    float4 s_acc = make_float4(0.f, 0.f, 0.f, 0.f);

    const int tf = tid >> 4;   // 0..15 -> f row group (4 rows each)
    const int td = tid & 15;   // 0..15 -> d col group (4 cols each)

    float4 pf_fk0 = fkb[(long long)(g0)      * 32];
    float4 pf_fk1 = fkb[(long long)(g0 + 16) * 32];
    float4 pf_v0  = vb [(long long)(g0)      * 32];
    float4 pf_v1  = vb [(long long)(g0 + 16) * 32];

    for (int c0 = 0; c0 < GG; c0 += 32) {
        __syncthreads();   // previous compute done; safe to overwrite LDS
        *(float4*)&fk_t[g0][f4 * 4]      = pf_fk0;
        *(float4*)&fk_t[g0 + 16][f4 * 4] = pf_fk1;
        *(float4*)&v_t[g0][f4 * 4]       = pf_v0;
        *(float4*)&v_t[g0 + 16][f4 * 4]  = pf_v1;
        s_acc.x += pf_fk0.x + pf_fk1.x;
        s_acc.y += pf_fk0.y + pf_fk1.y;
        s_acc.z += pf_fk0.z + pf_fk1.z;
        s_acc.w += pf_fk0.w + pf_fk1.w;
        __syncthreads();

        if (c0 + 32 < GG) {   // issue next chunk's loads; land during FMAs
            pf_fk0 = fkb[(long long)(c0 + 32 + g0)      * 32];
            pf_fk1 = fkb[(long long)(c0 + 32 + g0 + 16) * 32];
            pf_v0  = vb [(long long)(c0 + 32 + g0)      * 32];
            pf_v1  = vb [(long long)(c0 + 32 + g0 + 16) * 32];
        }

#pragma unroll 4
        for (int g = 0; g < 32; ++g) {
            float fa[4], vv[4];
#pragma unroll
            for (int a = 0; a < 4; ++a) fa[a] = fk_t[g][tf * 4 + a];
#pragma unroll
            for (int b2 = 0; b2 < 4; ++b2) vv[b2] = v_t[g][td * 4 + b2];
#pragma unroll
            for (int a = 0; a < 4; ++a)
#pragma unroll
                for (int b2 = 0; b2 < 4; ++b2)
                    acc[a][b2] += fa[a] * vv[b2];
        }
    }

    float* Hb = H_out + (long long)bh * FF * DD
              + (long long)(fq * 64 + tf * 4) * DD + dq * 64 + td * 4;
#pragma unroll
    for (int a = 0; a < 4; ++a)
        *(float4*)&Hb[(long long)a * DD] =
            make_float4(acc[a][0], acc[a][1], acc[a][2], acc[a][3]);

    s4[tid] = s_acc;
    __syncthreads();
    if (dq == 0 && tid < 16) {
        float4 s = make_float4(0.f, 0.f, 0.f, 0.f);
#pragma unroll
        for (int r = 0; r < 16; ++r) {
            float4 p = s4[r * 16 + tid];
            s.x += p.x; s.y += p.y; s.z += p.z; s.w += p.w;
        }
        *(float4*)&S_out[(long long)bh * FF + fq * 64 + tid * 4] = s;
    }
}

// ---------------------------------------------------------------------------
extern "C" void kernel_launch(void* const* d_in, const int* in_sizes, int n_in,
                              void* d_out, int out_size, void* d_ws, size_t ws_size,
                              hipStream_t stream) {
    const float* k_c      = (const float*)d_in[0];
    const float* v_c      = (const float*)d_in[1];
    const float* fk_c     = (const float*)d_in[2];
    const float* score_c  = (const float*)d_in[3];
    const float* K_win    = (const float*)d_in[4];
    const float* V_win    = (const float*)d_in[5];
    const float* K_top    = (const float*)d_in[6];
    const float* V_top    = (const float*)d_in[7];
    const float* FK_top   = (const float*)d_in[8];
    const float* heap_val = (const float*)d_in[9];
    const int*   heap_idx = (const int*)d_in[10];
    const int*   tokens   = (const int*)d_in[11];

    float* out = (float*)d_out;

    const size_t SZ_WIN = (size_t)BB * HH * CC * DD;   // 2,097,152
    const size_t SZ_TOP = (size_t)BB * HH * GG * DD;   // 16,777,216
    const size_t SZ_VAL = (size_t)BB * HH * GG;        //   131,072
    const size_t SZ_H   = (size_t)BB * HH * FF * DD;   // 1,048,576

    float* o_Kwin  = out;
    float* o_Vwin  = o_Kwin  + SZ_WIN;
    float* o_Ktop  = o_Vwin  + SZ_WIN;
    float* o_Vtop  = o_Ktop  + SZ_TOP;
    float* o_FKtop = o_Vtop  + SZ_TOP;
    float* o_val   = o_FKtop + SZ_TOP;
    float* o_idx   = o_val   + SZ_VAL;
    float* o_H     = o_idx   + SZ_VAL;
    float* o_S     = o_H     + SZ_H;

    int* selws = (int*)d_ws;   // B*H*G ints = 512 KB

    // 1) top-k selection via O(n^2) ranking (writes new_val, new_idx, sel)
    rank_topk_kernel<<<BB * HH * 9, 256, 0, stream>>>(
        heap_val, heap_idx, score_c, tokens, o_val, o_idx, selws);

    // 2) gather survivors into K_top_new / V_top_new / FK_top_new
    {
        long long nthreads = 3LL * BB * HH * GG * 32;  // 12,582,912
        int blocks = (int)(nthreads / 256);             // 49,152
        gather_topk_kernel<<<blocks, 256, 0, stream>>>(
            (const float4*)K_top, (const float4*)V_top, (const float4*)FK_top,
            (const float4*)k_c, (const float4*)v_c, (const float4*)fk_c,
            selws, (float4*)o_Ktop, (float4*)o_Vtop, (float4*)o_FKtop);
    }

    // 3) sliding window shift
    {
        int nthreads = 2 * BB * HH * CC * 32;          // 1,048,576
        window_kernel<<<nthreads / 256, 256, 0, stream>>>(
            (const float4*)K_win, (const float4*)V_win,
            (const float4*)k_c, (const float4*)v_c,
            (float4*)o_Kwin, (float4*)o_Vwin);
    }

    // 4) low-rank sums from the just-written FK_top_new / V_top_new
    hsum_kernel<<<4 * BB * HH, 256, 0, stream>>>(
        (const float4*)o_FKtop, (const float4*)o_Vtop, o_H, o_S);
}

// Round 4
// 150.817 us; speedup vs baseline: 3.2178x; 1.3919x over previous
//
#include <hip/hip_runtime.h>
#include <stdint.h>

#define BB 2
#define HH 32
#define CC 256
#define DD 128
#define GG 2048
#define FF 128
#define NCAT (GG + CC)   // 2304

// ---------------------------------------------------------------------------
// Kernel 1: per-(b,h) stable descending top-G via O(n^2) ranking.
// key = (float_bits << 12) | (4095 - j): values are uniform [0,1) => >= 0,
// so raw float bits are monotone; lower original index j wins ties (matching
// jax.lax.top_k). Keys are unique => rank = #{keys > mine} is exact.
// ---------------------------------------------------------------------------
__global__ __launch_bounds__(256) void rank_topk_kernel(
    const float* __restrict__ heap_val, const int* __restrict__ heap_idx,
    const float* __restrict__ score_c, const int* __restrict__ tokens_seen,
    float* __restrict__ out_val, float* __restrict__ out_idx,
    int* __restrict__ selws)
{
    __shared__ uint64_t keys[NCAT];          // 18 KB

    const int blk = blockIdx.x;
    const int bh  = blk / 9;
    const int seg = blk - bh * 9;
    const int tid = threadIdx.x;

    const float* hv = heap_val + (size_t)bh * GG;
    const float* sc = score_c  + (size_t)bh * CC;

    for (int i = tid; i < NCAT; i += 256) {
        uint32_t fb = (i < GG) ? __float_as_uint(hv[i])
                               : __float_as_uint(sc[i - GG]);
        keys[i] = ((uint64_t)fb << 12) | (uint64_t)(4095 - i);
    }
    __syncthreads();

    const int cand = seg * 256 + tid;        // 0..2303
    const uint64_t my = keys[cand];

    int rank = 0;
    const ulonglong2* k2 = (const ulonglong2*)keys;
#pragma unroll 4
    for (int j = 0; j < NCAT / 2; ++j) {     // uniform addr -> LDS broadcast
        ulonglong2 p = k2[j];
        rank += (p.x > my) + (p.y > my);
    }

    if (rank < GG) {
        const size_t o = (size_t)bh * GG + rank;
        out_val[o] = __uint_as_float((uint32_t)(my >> 12));
        int j = 4095 - (int)(my & 0xFFFull);
        int gidx = (j < GG) ? heap_idx[(size_t)bh * GG + j]
                            : (tokens_seen[0] + (j - GG));
        out_idx[o] = (float)gidx;            // exact (<= 4351)
        selws[o] = j;
    }
}

// ---------------------------------------------------------------------------
// Kernel 2 (fused): gather K/V/FK survivors AND accumulate partial
// H[f][d] = sum_g FK[g][f] * V[g][d] while the rows pass through.
// Grid: 64 bh x 4 segments = 256 blocks, 256 threads. Each block owns 512
// g-rows, keeps a full 128x128 fp32 partial-H (8x8 regs/thread), stages
// FK/V in 16-row LDS tiles, prefetches the next tile into registers.
// ---------------------------------------------------------------------------
__global__ __launch_bounds__(256) void fused_gather_hsum_kernel(
    const float4* __restrict__ K_top, const float4* __restrict__ V_top,
    const float4* __restrict__ FK_top,
    const float4* __restrict__ k_c, const float4* __restrict__ v_c,
    const float4* __restrict__ fk_c,
    const int* __restrict__ selws,
    float4* __restrict__ oK, float4* __restrict__ oV, float4* __restrict__ oFK,
    float* __restrict__ Hpart, float* __restrict__ Spart)
{
    __shared__ float fk_t[16][128];     // 8 KB
    __shared__ float v_t[16][128];      // 8 KB
    __shared__ float4 sredA[256];       // 4 KB
    __shared__ float4 sredB[256];       // 4 KB

    const int bh  = blockIdx.x >> 2;
    const int seg = blockIdx.x & 3;
    const int tid = threadIdx.x;
    const int r   = tid >> 4;           // 0..15 row in tile (staging role)
    const int q   = tid & 15;           // float4 col in row  (staging role)
    const int tf  = tid >> 4;           // f-group (compute role)
    const int td  = tid & 15;           // d-group (compute role)

    const long long topQ = (long long)bh * GG * 32;   // quad offsets
    const long long chkQ = (long long)bh * CC * 32;
    const int row0 = seg * 512;
    const int selbase = bh * GG + row0;

    float acc[8][8];
#pragma unroll
    for (int a = 0; a < 8; ++a)
#pragma unroll
        for (int b2 = 0; b2 < 8; ++b2) acc[a][b2] = 0.f;
    float4 sA = make_float4(0.f, 0.f, 0.f, 0.f);
    float4 sB = make_float4(0.f, 0.f, 0.f, 0.f);

    // ---- prologue: prefetch tile 0 ----
    int j = selws[selbase + r];
    const float4* bK = (j < GG) ? K_top  + topQ + (long long)j * 32
                                : k_c    + chkQ + (long long)(j - GG) * 32;
    const float4* bV = (j < GG) ? V_top  + topQ + (long long)j * 32
                                : v_c    + chkQ + (long long)(j - GG) * 32;
    const float4* bF = (j < GG) ? FK_top + topQ + (long long)j * 32
                                : fk_c   + chkQ + (long long)(j - GG) * 32;
    float4 pk0 = bK[q], pk1 = bK[q + 16];
    float4 pv0 = bV[q], pv1 = bV[q + 16];
    float4 pf0 = bF[q], pf1 = bF[q + 16];

    for (int tile = 0; tile < 32; ++tile) {
        const int gr = row0 + tile * 16;
        int jn = 0;
        if (tile < 31) jn = selws[selbase + tile * 16 + 16 + r];  // early issue

        __syncthreads();   // previous tile's compute done
        // stage LDS + write gather outputs from prefetched registers
        *(float4*)&fk_t[r][q * 4]        = pf0;
        *(float4*)&fk_t[r][(q + 16) * 4] = pf1;
        *(float4*)&v_t[r][q * 4]         = pv0;
        *(float4*)&v_t[r][(q + 16) * 4]  = pv1;
        const long long ob = ((long long)bh * GG + gr + r) * 32;
        oFK[ob + q] = pf0;  oFK[ob + q + 16] = pf1;
        oV[ob + q]  = pv0;  oV[ob + q + 16]  = pv1;
        oK[ob + q]  = pk0;  oK[ob + q + 16]  = pk1;
        sA.x += pf0.x; sA.y += pf0.y; sA.z += pf0.z; sA.w += pf0.w;
        sB.x += pf1.x; sB.y += pf1.y; sB.z += pf1.z; sB.w += pf1.w;
        __syncthreads();

        // issue next tile's loads; they land during the FMAs below
        if (tile < 31) {
            const float4* nK = (jn < GG) ? K_top  + topQ + (long long)jn * 32
                                         : k_c    + chkQ + (long long)(jn - GG) * 32;
            const float4* nV = (jn < GG) ? V_top  + topQ + (long long)jn * 32
                                         : v_c    + chkQ + (long long)(jn - GG) * 32;
            const float4* nF = (jn < GG) ? FK_top + topQ + (long long)jn * 32
                                         : fk_c   + chkQ + (long long)(jn - GG) * 32;
            pk0 = nK[q]; pk1 = nK[q + 16];
            pv0 = nV[q]; pv1 = nV[q + 16];
            pf0 = nF[q]; pf1 = nF[q + 16];
        }

#pragma unroll 4
        for (int g = 0; g < 16; ++g) {
            float4 fa0 = *(const float4*)&fk_t[g][tf * 8];
            float4 fa1 = *(const float4*)&fk_t[g][tf * 8 + 4];
            float4 vv0 = *(const float4*)&v_t[g][td * 8];
            float4 vv1 = *(const float4*)&v_t[g][td * 8 + 4];
            float fa[8] = {fa0.x, fa0.y, fa0.z, fa0.w, fa1.x, fa1.y, fa1.z, fa1.w};
            float vv[8] = {vv0.x, vv0.y, vv0.z, vv0.w, vv1.x, vv1.y, vv1.z, vv1.w};
#pragma unroll
            for (int a = 0; a < 8; ++a)
#pragma unroll
                for (int b2 = 0; b2 < 8; ++b2)
                    acc[a][b2] += fa[a] * vv[b2];
        }
    }

    // ---- write partial H ----
    float* Hb = Hpart + (long long)blockIdx.x * (FF * DD);
#pragma unroll
    for (int a = 0; a < 8; ++a) {
        *(float4*)&Hb[(long long)(tf * 8 + a) * DD + td * 8] =
            make_float4(acc[a][0], acc[a][1], acc[a][2], acc[a][3]);
        *(float4*)&Hb[(long long)(tf * 8 + a) * DD + td * 8 + 4] =
            make_float4(acc[a][4], acc[a][5], acc[a][6], acc[a][7]);
    }

    // ---- partial S: reduce over the 16 row-groups ----
    __syncthreads();
    sredA[tid] = sA; sredB[tid] = sB;
    __syncthreads();
    if (tid < 16) {
        float4 a = make_float4(0.f, 0.f, 0.f, 0.f);
        float4 b = make_float4(0.f, 0.f, 0.f, 0.f);
#pragma unroll
        for (int k = 0; k < 16; ++k) {
            float4 pa = sredA[k * 16 + tid];
            float4 pb = sredB[k * 16 + tid];
            a.x += pa.x; a.y += pa.y; a.z += pa.z; a.w += pa.w;
            b.x += pb.x; b.y += pb.y; b.z += pb.z; b.w += pb.w;
        }
        float* Sb = Spart + (long long)blockIdx.x * FF;
        *(float4*)&Sb[tid * 4]        = a;
        *(float4*)&Sb[(tid + 16) * 4] = b;
    }
}

// ---------------------------------------------------------------------------
// Kernel 3 (finish): window shift + reduce the 4 H/S partials per bh.
// Roles by blockIdx: [0,4096) window, [4096,5120) H-reduce, [5120,5128) S.
// ---------------------------------------------------------------------------
__global__ __launch_bounds__(256) void finish_kernel(
    const float4* __restrict__ Hpart4, const float4* __restrict__ Spart4,
    const float4* __restrict__ K_win, const float4* __restrict__ V_win,
    const float4* __restrict__ k_c, const float4* __restrict__ v_c,
    float4* __restrict__ oKw, float4* __restrict__ oVw,
    float4* __restrict__ oH, float4* __restrict__ oS)
{
    const int b = blockIdx.x;
    const int tid = threadIdx.x;

    if (b < 4096) {
        // window shift: 2 arrays x 524288 quads
        const int QPA = BB * HH * CC * 32;
        int t = b * 256 + tid;
        int arr = t / QPA;
        int rem = t - arr * QPA;
        int row = rem >> 5;
        int q   = rem & 31;
        int bh  = row >> 8;
        int c   = row & 255;
        const float4* win = arr ? V_win : K_win;
        const float4* chk = arr ? v_c : k_c;
        float4 val = (c < CC - 1)
            ? win[((long long)bh * CC + c + 1) * 32 + q]
            : chk[((long long)bh * CC + (CC - 1)) * 32 + q];
        (arr ? oVw : oKw)[(long long)row * 32 + q] = val;
    } else if (b < 4096 + 1024) {
        // H reduce: 262144 float4 total, 4096 per bh
        int p  = (b - 4096) * 256 + tid;
        int bh = p >> 12;
        int off = p & 4095;
        float4 s = make_float4(0.f, 0.f, 0.f, 0.f);
#pragma unroll
        for (int s4 = 0; s4 < 4; ++s4) {
            float4 v = Hpart4[(((long long)bh * 4 + s4) << 12) + off];
            s.x += v.x; s.y += v.y; s.z += v.z; s.w += v.w;
        }
        oH[p] = s;
    } else {
        // S reduce: 2048 float4 total, 32 per bh
        int p = (b - 5120) * 256 + tid;
        int bh = p >> 5;
        int off = p & 31;
        float4 s = make_float4(0.f, 0.f, 0.f, 0.f);
#pragma unroll
        for (int s4 = 0; s4 < 4; ++s4) {
            float4 v = Spart4[((long long)bh * 4 + s4) * 32 + off];
            s.x += v.x; s.y += v.y; s.z += v.z; s.w += v.w;
        }
        oS[p] = s;
    }
}

// ---------------------------------------------------------------------------
// Fallback kernels (used only if ws_size is too small for H partials).
// ---------------------------------------------------------------------------
__global__ __launch_bounds__(256) void gather_topk_kernel(
    const float4* __restrict__ K_top, const float4* __restrict__ V_top,
    const float4* __restrict__ FK_top,
    const float4* __restrict__ k_c, const float4* __restrict__ v_c,
    const float4* __restrict__ fk_c,
    const int* __restrict__ selws,
    float4* __restrict__ oK, float4* __restrict__ oV, float4* __restrict__ oFK)
{
    const long long ROWQ = (long long)BB * HH * GG * 32;
    long long t = (long long)blockIdx.x * 256 + threadIdx.x;
    int arr = (int)(t / ROWQ);
    long long rem = t - (long long)arr * ROWQ;
    int row = (int)(rem >> 5);
    int q   = (int)(rem & 31);
    int bh  = row >> 11;
    int j   = selws[row];

    const float4* topsrc = (arr == 0) ? K_top : ((arr == 1) ? V_top : FK_top);
    const float4* chksrc = (arr == 0) ? k_c   : ((arr == 1) ? v_c   : fk_c);
    float4*       dst    = (arr == 0) ? oK    : ((arr == 1) ? oV    : oFK);

    float4 val;
    if (j < GG) val = topsrc[((long long)bh * GG + j) * 32 + q];
    else        val = chksrc[((long long)bh * CC + (j - GG)) * 32 + q];
    dst[(long long)row * 32 + q] = val;
}

__global__ __launch_bounds__(256) void window_kernel(
    const float4* __restrict__ K_win, const float4* __restrict__ V_win,
    const float4* __restrict__ k_c, const float4* __restrict__ v_c,
    float4* __restrict__ oKw, float4* __restrict__ oVw)
{
    const int QPA = BB * HH * CC * 32;
    int t = blockIdx.x * 256 + threadIdx.x;
    int arr = t / QPA;
    int rem = t - arr * QPA;
    int row = rem >> 5;
    int q   = rem & 31;
    int bh  = row >> 8;
    int c   = row & 255;

    const float4* win = arr ? V_win : K_win;
    const float4* chk = arr ? v_c : k_c;
    float4 val = (c < CC - 1)
        ? win[((long long)bh * CC + c + 1) * 32 + q]
        : chk[((long long)bh * CC + (CC - 1)) * 32 + q];
    (arr ? oVw : oKw)[(long long)row * 32 + q] = val;
}

__global__ __launch_bounds__(256) void hsum_kernel(
    const float4* __restrict__ FKq, const float4* __restrict__ Vq,
    float* __restrict__ H_out, float* __restrict__ S_out)
{
    __shared__ float fk_t[32][68];
    __shared__ float v_t[32][68];
    __shared__ float4 s4[256];

    const int bx  = blockIdx.x;
    const int bh  = bx >> 2;
    const int fq  = (bx >> 1) & 1;
    const int dq  = bx & 1;
    const int tid = threadIdx.x;
    const int g0 = tid >> 4;
    const int f4 = tid & 15;

    const float4* fkb = FKq + (long long)bh * GG * 32 + fq * 16 + f4;
    const float4* vb  = Vq  + (long long)bh * GG * 32 + dq * 16 + f4;

    float acc[4][4];
#pragma unroll
    for (int a = 0; a < 4; ++a)
#pragma unroll
        for (int b2 = 0; b2 < 4; ++b2) acc[a][b2] = 0.f;
    float4 s_acc = make_float4(0.f, 0.f, 0.f, 0.f);
    const int tf = tid >> 4, td = tid & 15;

    float4 pf_fk0 = fkb[(long long)(g0)      * 32];
    float4 pf_fk1 = fkb[(long long)(g0 + 16) * 32];
    float4 pf_v0  = vb [(long long)(g0)      * 32];
    float4 pf_v1  = vb [(long long)(g0 + 16) * 32];

    for (int c0 = 0; c0 < GG; c0 += 32) {
        __syncthreads();
        *(float4*)&fk_t[g0][f4 * 4]      = pf_fk0;
        *(float4*)&fk_t[g0 + 16][f4 * 4] = pf_fk1;
        *(float4*)&v_t[g0][f4 * 4]       = pf_v0;
        *(float4*)&v_t[g0 + 16][f4 * 4]  = pf_v1;
        s_acc.x += pf_fk0.x + pf_fk1.x;
        s_acc.y += pf_fk0.y + pf_fk1.y;
        s_acc.z += pf_fk0.z + pf_fk1.z;
        s_acc.w += pf_fk0.w + pf_fk1.w;
        __syncthreads();

        if (c0 + 32 < GG) {
            pf_fk0 = fkb[(long long)(c0 + 32 + g0)      * 32];
            pf_fk1 = fkb[(long long)(c0 + 32 + g0 + 16) * 32];
            pf_v0  = vb [(long long)(c0 + 32 + g0)      * 32];
            pf_v1  = vb [(long long)(c0 + 32 + g0 + 16) * 32];
        }

#pragma unroll 4
        for (int g = 0; g < 32; ++g) {
            float fa[4], vv[4];
#pragma unroll
            for (int a = 0; a < 4; ++a) fa[a] = fk_t[g][tf * 4 + a];
#pragma unroll
            for (int b2 = 0; b2 < 4; ++b2) vv[b2] = v_t[g][td * 4 + b2];
#pragma unroll
            for (int a = 0; a < 4; ++a)
#pragma unroll
                for (int b2 = 0; b2 < 4; ++b2)
                    acc[a][b2] += fa[a] * vv[b2];
        }
    }

    float* Hb = H_out + (long long)bh * FF * DD
              + (long long)(fq * 64 + tf * 4) * DD + dq * 64 + td * 4;
#pragma unroll
    for (int a = 0; a < 4; ++a)
        *(float4*)&Hb[(long long)a * DD] =
            make_float4(acc[a][0], acc[a][1], acc[a][2], acc[a][3]);

    s4[tid] = s_acc;
    __syncthreads();
    if (dq == 0 && tid < 16) {
        float4 s = make_float4(0.f, 0.f, 0.f, 0.f);
#pragma unroll
        for (int r = 0; r < 16; ++r) {
            float4 p = s4[r * 16 + tid];
            s.x += p.x; s.y += p.y; s.z += p.z; s.w += p.w;
        }
        *(float4*)&S_out[(long long)bh * FF + fq * 64 + tid * 4] = s;
    }
}

// ---------------------------------------------------------------------------
extern "C" void kernel_launch(void* const* d_in, const int* in_sizes, int n_in,
                              void* d_out, int out_size, void* d_ws, size_t ws_size,
                              hipStream_t stream) {
    const float* k_c      = (const float*)d_in[0];
    const float* v_c      = (const float*)d_in[1];
    const float* fk_c     = (const float*)d_in[2];
    const float* score_c  = (const float*)d_in[3];
    const float* K_win    = (const float*)d_in[4];
    const float* V_win    = (const float*)d_in[5];
    const float* K_top    = (const float*)d_in[6];
    const float* V_top    = (const float*)d_in[7];
    const float* FK_top   = (const float*)d_in[8];
    const float* heap_val = (const float*)d_in[9];
    const int*   heap_idx = (const int*)d_in[10];
    const int*   tokens   = (const int*)d_in[11];

    float* out = (float*)d_out;

    const size_t SZ_WIN = (size_t)BB * HH * CC * DD;   // 2,097,152
    const size_t SZ_TOP = (size_t)BB * HH * GG * DD;   // 16,777,216
    const size_t SZ_VAL = (size_t)BB * HH * GG;        //   131,072
    const size_t SZ_H   = (size_t)BB * HH * FF * DD;   // 1,048,576

    float* o_Kwin  = out;
    float* o_Vwin  = o_Kwin  + SZ_WIN;
    float* o_Ktop  = o_Vwin  + SZ_WIN;
    float* o_Vtop  = o_Ktop  + SZ_TOP;
    float* o_FKtop = o_Vtop  + SZ_TOP;
    float* o_val   = o_FKtop + SZ_TOP;
    float* o_idx   = o_val   + SZ_VAL;
    float* o_H     = o_idx   + SZ_VAL;
    float* o_S     = o_H     + SZ_H;

    // workspace layout
    const size_t selN   = (size_t)BB * HH * GG;                    // 131072 ints
    const size_t hpartN = (size_t)256 * FF * DD;                   // 4,194,304 floats
    const size_t spartN = (size_t)256 * FF;                        //    32,768 floats
    const size_t need = selN * sizeof(int) + (hpartN + spartN) * sizeof(float);

    int*   selws = (int*)d_ws;
    float* Hpart = (float*)(selws + selN);
    float* Spart = Hpart + hpartN;

    // 1) top-k selection via O(n^2) ranking
    rank_topk_kernel<<<BB * HH * 9, 256, 0, stream>>>(
        heap_val, heap_idx, score_c, tokens, o_val, o_idx, selws);

    if (ws_size >= need) {
        // 2) fused gather + partial H/S
        fused_gather_hsum_kernel<<<4 * BB * HH, 256, 0, stream>>>(
            (const float4*)K_top, (const float4*)V_top, (const float4*)FK_top,
            (const float4*)k_c, (const float4*)v_c, (const float4*)fk_c,
            selws, (float4*)o_Ktop, (float4*)o_Vtop, (float4*)o_FKtop,
            Hpart, Spart);

        // 3) window + partial reduction
        finish_kernel<<<4096 + 1024 + 8, 256, 0, stream>>>(
            (const float4*)Hpart, (const float4*)Spart,
            (const float4*)K_win, (const float4*)V_win,
            (const float4*)k_c, (const float4*)v_c,
            (float4*)o_Kwin, (float4*)o_Vwin, (float4*)o_H, (float4*)o_S);
    } else {
        // fallback: round-3 structure
        long long nthreads = 3LL * BB * HH * GG * 32;
        gather_topk_kernel<<<(int)(nthreads / 256), 256, 0, stream>>>(
            (const float4*)K_top, (const float4*)V_top, (const float4*)FK_top,
            (const float4*)k_c, (const float4*)v_c, (const float4*)fk_c,
            selws, (float4*)o_Ktop, (float4*)o_Vtop, (float4*)o_FKtop);
        int nthreads2 = 2 * BB * HH * CC * 32;
        window_kernel<<<nthreads2 / 256, 256, 0, stream>>>(
            (const float4*)K_win, (const float4*)V_win,
            (const float4*)k_c, (const float4*)v_c,
            (float4*)o_Kwin, (float4*)o_Vwin);
        hsum_kernel<<<4 * BB * HH, 256, 0, stream>>>(
            (const float4*)o_FKtop, (const float4*)o_Vtop, o_H, o_S);
    }
}